// Round 4
// baseline (2071.987 us; speedup 1.0000x reference)
//
#include <hip/hip_runtime.h>
#include <hip/hip_bf16.h>

// 4-layer SRU. L=4, B=32, T=512, D=512, V=1000.
// Inputs f32 (device-verified via detect), ids/mask int32, OUTPUT f32.
// X lives in d_out, (B,T,D) f32 layout — final layer's scan writes the answer.
// ws: flags + carry(B*D f32) + U chunk (chunkT*B*3D f32), chunkT adaptive.

#define LAYERS 4
#define BB 32
#define TT 512
#define DD 512
#define N3 1536
#define MROWS (TT * BB)
#define WPL ((size_t)DD * N3)  // W elems per layer

typedef unsigned short u16;

__device__ __forceinline__ float b2f(u16 u) {
  union { unsigned int i; float f; } x;
  x.i = ((unsigned int)u) << 16;
  return x.f;
}

// ---- dtype detection (flags[0]: floats are f32, [1]: mask bytes, [2]: ids int64)
__global__ void detect_kernel(const u16* __restrict__ emb_u,
                              const int* __restrict__ mask_i,
                              const int* __restrict__ ids_i,
                              int* __restrict__ flags) {
  __shared__ int cnt[3];
  __shared__ int zc;
  int tid = threadIdx.x;
  if (tid < 3) cnt[tid] = 0;
  if (tid == 0) zc = 0;
  __syncthreads();
  int bad = 0, zero_even = 0;
  for (int i = tid; i < 8192; i += 256) {
    u16 u = emb_u[i];
    unsigned e = (u >> 7) & 0xFF;
    if (e >= 0x8F) bad++;
    if ((i & 1) == 0 && u == 0) zero_even++;
  }
  if (bad) atomicAdd(&cnt[0], bad);
  if (zero_even) atomicAdd(&zc, zero_even);
  if (tid < 64) {
    unsigned vv = (unsigned)mask_i[tid];
    if (vv > 1u) atomicAdd(&cnt[1], 1);
  }
  if (tid < 256) {
    if (ids_i[2 * tid + 1] == 0) atomicAdd(&cnt[2], 1);
  }
  __syncthreads();
  if (tid == 0) {
    flags[0] = (cnt[0] > 64 || zc > 3000) ? 1 : 0;
    flags[1] = (cnt[1] > 0) ? 1 : 0;
    flags[2] = (cnt[2] >= 192) ? 1 : 0;
  }
}

// ---- embedding gather: X[b][t][d] = emb[ids[b][t]][d]  (X = d_out, (B,T,D))
__global__ void embed_kernel(const int* __restrict__ ids,
                             const void* __restrict__ emb,
                             float* __restrict__ X,
                             const int* __restrict__ flags) {
  int i = blockIdx.x * 256 + threadIdx.x;  // linear over (b,t,d)
  int d = i & (DD - 1);
  int bt = i >> 9;  // b*TT + t
  int id = flags[2] ? ids[2 * bt] : ids[bt];
  float val = flags[0] ? ((const float*)emb)[id * DD + d]
                       : b2f(((const u16*)emb)[id * DD + d]);
  X[i] = val;
}

// ---- GEMM: U_chunk[r,1536] = X[row_base+r, :] * W_l ; X is (B,T,D)
__global__ __launch_bounds__(256)
void gemm_kernel(const float* __restrict__ X, const void* __restrict__ Wv,
                 float* __restrict__ C, const int* __restrict__ flags,
                 int layer, int row_base) {
  __shared__ float As[8][128];
  __shared__ float Bs[8][128];
  const int row0 = blockIdx.x * 128;
  const int col0 = blockIdx.y * 128;
  const int tid = threadIdx.x;
  const int ff = flags[0];
  const int am = tid >> 1, ak = (tid & 1) * 4;
  const int bk = tid >> 5, bn = (tid & 31) * 4;
  const int tx = tid & 15, ty = tid >> 4;
  const size_t wbase = (size_t)layer * WPL;

  // global row = t*BB + b ; X offset = (b*TT + t)*DD + k
  const int ar = row_base + row0 + am;
  const size_t arow = ((size_t)(ar & 31) * TT + (ar >> 5)) * DD;

  float acc[8][8];
#pragma unroll
  for (int i = 0; i < 8; ++i)
#pragma unroll
    for (int j = 0; j < 8; ++j) acc[i][j] = 0.f;

  for (int k0 = 0; k0 < 512; k0 += 8) {
    float4 av = *(const float4*)(X + arow + k0 + ak);
    size_t woff = wbase + (size_t)(k0 + bk) * N3 + col0 + bn;
    float4 bv;
    if (ff) {
      bv = *(const float4*)((const float*)Wv + woff);
    } else {
      ushort4 u = *(const ushort4*)((const u16*)Wv + woff);
      bv = make_float4(b2f(u.x), b2f(u.y), b2f(u.z), b2f(u.w));
    }
    As[ak + 0][am] = av.x;
    As[ak + 1][am] = av.y;
    As[ak + 2][am] = av.z;
    As[ak + 3][am] = av.w;
    Bs[bk][bn + 0] = bv.x;
    Bs[bk][bn + 1] = bv.y;
    Bs[bk][bn + 2] = bv.z;
    Bs[bk][bn + 3] = bv.w;
    __syncthreads();
#pragma unroll
    for (int k = 0; k < 8; ++k) {
      float4 a0 = *(const float4*)&As[k][ty * 4];
      float4 a1 = *(const float4*)&As[k][64 + ty * 4];
      float4 b0 = *(const float4*)&Bs[k][tx * 4];
      float4 b1 = *(const float4*)&Bs[k][64 + tx * 4];
      float ar8[8] = {a0.x, a0.y, a0.z, a0.w, a1.x, a1.y, a1.z, a1.w};
      float br8[8] = {b0.x, b0.y, b0.z, b0.w, b1.x, b1.y, b1.z, b1.w};
#pragma unroll
      for (int i = 0; i < 8; ++i)
#pragma unroll
        for (int j = 0; j < 8; ++j) acc[i][j] = fmaf(ar8[i], br8[j], acc[i][j]);
    }
    __syncthreads();
  }
#pragma unroll
  for (int i = 0; i < 8; ++i) {
    int r = row0 + ((i < 4) ? (ty * 4 + i) : (64 + ty * 4 + (i - 4)));  // chunk-local
    *(float4*)&C[(size_t)r * N3 + col0 + tx * 4] =
        make_float4(acc[i][0], acc[i][1], acc[i][2], acc[i][3]);
    *(float4*)&C[(size_t)r * N3 + col0 + 64 + tx * 4] =
        make_float4(acc[i][4], acc[i][5], acc[i][6], acc[i][7]);
  }
}

// ---- SRU recurrence over one T-chunk; X = d_out (B,T,D), updated in place
__global__ __launch_bounds__(64)
void scan_kernel(const float* __restrict__ U, float* __restrict__ X,
                 const void* __restrict__ mask_p, const void* __restrict__ vbase,
                 const void* __restrict__ bbase, int layer,
                 const int* __restrict__ flags, float* __restrict__ carry,
                 int t0, int nt) {
  int idx = blockIdx.x * 64 + threadIdx.x;  // [0, B*D)
  int b = idx >> 9;
  int d = idx & 511;
  int ff = flags[0], fm = flags[1];
  size_t voff = (size_t)layer * 2 * DD;
  float vf, vr, bf_, br_;
  if (ff) {
    const float* vp = (const float*)vbase + voff;
    const float* bp2 = (const float*)bbase + voff;
    vf = vp[d]; vr = vp[DD + d]; bf_ = bp2[d]; br_ = bp2[DD + d];
  } else {
    const u16* vp = (const u16*)vbase + voff;
    const u16* bp2 = (const u16*)bbase + voff;
    vf = b2f(vp[d]); vr = b2f(vp[DD + d]); bf_ = b2f(bp2[d]); br_ = b2f(bp2[DD + d]);
  }
  const int* mi = (const int*)mask_p + b * TT;
  const unsigned char* mb = (const unsigned char*)mask_p + b * TT;

  float c = (t0 == 0) ? 0.f : carry[idx];
  float* Xrow = X + (size_t)b * TT * DD + d;  // + t*DD indexes time

  // preload first timestep
  const float* u0 = U + (size_t)b * N3 + d;
  float xt = u0[0], fp = u0[512], rp = u0[1024];
  float xin = Xrow[(size_t)t0 * DD];

  for (int tl = 0; tl < nt; ++tl) {
    int t = t0 + tl;
    float nxt = 0.f, nfp = 0.f, nrp = 0.f, nxi = 0.f;
    if (tl + 1 < nt) {  // prefetch next timestep (c-independent)
      const float* un = U + ((size_t)(tl + 1) * BB + b) * N3 + d;
      nxt = un[0];
      nfp = un[512];
      nrp = un[1024];
      nxi = Xrow[(size_t)(t + 1) * DD];
    }
    int m = fm ? (int)mb[t] : mi[t];
    float zf = fp + vf * c + bf_;
    float zr = rp + vr * c + br_;
    float f = 1.f / (1.f + __expf(-zf));
    float r = 1.f / (1.f + __expf(-zr));
    float cn = f * c + (1.f - f) * xt;
    float e2 = __expf(2.f * cn);
    float th = (e2 - 1.f) / (e2 + 1.f);
    float h = r * th + (1.f - r) * xin;
    bool pad = (m == 0);
    if (!pad) c = cn;
    Xrow[(size_t)t * DD] = pad ? 0.f : h;
    xt = nxt; fp = nfp; rp = nrp; xin = nxi;
  }
  carry[idx] = c;
}

__global__ void sentinel_kernel(float* out) { out[threadIdx.x] = 12345.f; }

extern "C" void kernel_launch(void* const* d_in, const int* in_sizes, int n_in,
                              void* d_out, int out_size, void* d_ws, size_t ws_size,
                              hipStream_t stream) {
  const int* ids = (const int*)d_in[0];
  const void* mask = d_in[1];
  const void* emb = d_in[2];
  const void* W = d_in[3];
  const void* v = d_in[4];
  const void* bp = d_in[5];

  char* ws = (char*)d_ws;
  int* flags = (int*)ws;                    // [0, 4096)
  float* carry = (float*)(ws + 4096);       // B*D f32 = 64 KiB
  const size_t offU = 69632;
  const size_t perT = (size_t)BB * N3 * 4;  // 196608 B per timestep of U

  const int cand[8] = {512, 256, 128, 64, 32, 16, 8, 4};
  int chunkT = 0;
  for (int i = 0; i < 8; ++i) {
    if (ws_size >= offU + (size_t)cand[i] * perT) { chunkT = cand[i]; break; }
  }
  if (!chunkT) {
    sentinel_kernel<<<1, 256, 0, stream>>>((float*)d_out);
    return;
  }

  float* X = (float*)d_out;           // (B,T,D) f32 — the output arena
  float* U = (float*)(ws + offU);

  detect_kernel<<<1, 256, 0, stream>>>((const u16*)emb, (const int*)mask,
                                       (const int*)ids, flags);
  embed_kernel<<<MROWS * DD / 256, 256, 0, stream>>>(ids, emb, X, flags);

  int nch = TT / chunkT;
  for (int l = 0; l < LAYERS; ++l) {
    for (int ch = 0; ch < nch; ++ch) {
      int t0 = ch * chunkT;
      dim3 g(chunkT * BB / 128, N3 / 128);
      gemm_kernel<<<g, 256, 0, stream>>>(X, W, U, flags, l, t0 * BB);
      scan_kernel<<<BB * DD / 64, 64, 0, stream>>>(U, X, mask, v, bp, l,
                                                   flags, carry, t0, chunkT);
    }
  }
}

// Round 5
// 1585.844 us; speedup vs baseline: 1.3066x; 1.3066x over previous
//
#include <hip/hip_runtime.h>
#include <hip/hip_bf16.h>

// 4-layer SRU. L=4, B=32, T=512, D=512, V=1000. f32 inputs, f32 output.
// R4: MFMA-split GEMM (U = Xh*Wh + Xh*Wl + Xl*Wh as virtual K=1536 bf16 GEMM)
//     + 8-deep prefetch scan. X f32 lives in d_out (B,T,D); Xh/Xl bf16 (T,B,D)
//     in ws; W pre-split+transposed to [l][hi/lo][n][k] bf16 in ws.

#define LAYERS 4
#define BB 32
#define TT 512
#define DD 512
#define N3 1536
#define MROWS (TT * BB)
#define WPL ((size_t)DD * N3)   // 786432 elems per layer (also [n][k] = 1536*512)
#define PF 8

typedef unsigned short u16;
typedef short bshort8 __attribute__((ext_vector_type(8)));
typedef unsigned short ushort8v __attribute__((ext_vector_type(8)));
typedef float f32x4 __attribute__((ext_vector_type(4)));

__device__ __forceinline__ float b2f(u16 u) {
  union { unsigned int i; float f; } x;
  x.i = ((unsigned int)u) << 16;
  return x.f;
}
__device__ __forceinline__ u16 f2b(float f) {  // RNE
  union { float f; unsigned int i; } x;
  x.f = f;
  unsigned int r = (x.i + 0x7FFFu + ((x.i >> 16) & 1u)) >> 16;
  return (u16)r;
}

// ---- dtype detection (flags[0]: floats f32, [1]: mask bytes, [2]: ids int64)
__global__ void detect_kernel(const u16* __restrict__ emb_u,
                              const int* __restrict__ mask_i,
                              const int* __restrict__ ids_i,
                              int* __restrict__ flags) {
  __shared__ int cnt[3];
  __shared__ int zc;
  int tid = threadIdx.x;
  if (tid < 3) cnt[tid] = 0;
  if (tid == 0) zc = 0;
  __syncthreads();
  int bad = 0, zero_even = 0;
  for (int i = tid; i < 8192; i += 256) {
    u16 u = emb_u[i];
    unsigned e = (u >> 7) & 0xFF;
    if (e >= 0x8F) bad++;
    if ((i & 1) == 0 && u == 0) zero_even++;
  }
  if (bad) atomicAdd(&cnt[0], bad);
  if (zero_even) atomicAdd(&zc, zero_even);
  if (tid < 64) {
    unsigned vv = (unsigned)mask_i[tid];
    if (vv > 1u) atomicAdd(&cnt[1], 1);
  }
  if (tid < 256) {
    if (ids_i[2 * tid + 1] == 0) atomicAdd(&cnt[2], 1);
  }
  __syncthreads();
  if (tid == 0) {
    flags[0] = (cnt[0] > 64 || zc > 3000) ? 1 : 0;
    flags[1] = (cnt[1] > 0) ? 1 : 0;
    flags[2] = (cnt[2] >= 192) ? 1 : 0;
  }
}

// ---- W split+transpose: Wst[l][s][n][k] bf16, s=0 hi, s=1 lo -----------
__global__ __launch_bounds__(256)
void wprep_kernel(const void* __restrict__ W, u16* __restrict__ Wst,
                  const int* __restrict__ flags) {
  __shared__ float tileW[32][33];
  int l = blockIdx.z;
  int k0 = blockIdx.x * 32;
  int n0 = blockIdx.y * 32;
  int tx = threadIdx.x & 31;
  int ty = threadIdx.x >> 5;  // 0..7
  int ff = flags[0];
  const float* Wf = (const float*)W + (size_t)l * WPL;
  const u16* Wb = (const u16*)W + (size_t)l * WPL;
  for (int kk = ty; kk < 32; kk += 8) {
    size_t off = (size_t)(k0 + kk) * N3 + n0 + tx;
    tileW[kk][tx] = ff ? Wf[off] : b2f(Wb[off]);
  }
  __syncthreads();
  u16* hiP = Wst + (size_t)l * 2 * WPL;
  u16* loP = hiP + WPL;
  for (int nn = ty; nn < 32; nn += 8) {
    float x = tileW[tx][nn];
    u16 hi = f2b(x);
    u16 lo = f2b(x - b2f(hi));
    size_t o = (size_t)(n0 + nn) * DD + k0 + tx;
    hiP[o] = hi;
    loP[o] = lo;
  }
}

// ---- embedding: X f32 (B,T,D) = d_out; Xh/Xl bf16 (T,B,D) --------------
__global__ void embed_kernel(const int* __restrict__ ids,
                             const void* __restrict__ emb,
                             float* __restrict__ X,
                             u16* __restrict__ Xh, u16* __restrict__ Xl,
                             const int* __restrict__ flags) {
  int i = blockIdx.x * 256 + threadIdx.x;  // (t,b,d) linear
  int d = i & (DD - 1);
  int tb = i >> 9;
  int b = tb & (BB - 1);
  int t = tb >> 5;
  int ii = b * TT + t;
  int id = flags[2] ? ids[2 * ii] : ids[ii];
  float val = flags[0] ? ((const float*)emb)[id * DD + d]
                       : b2f(((const u16*)emb)[id * DD + d]);
  X[((size_t)b * TT + t) * DD + d] = val;
  u16 hi = f2b(val);
  Xh[i] = hi;
  Xl[i] = f2b(val - b2f(hi));
}

// ---- MFMA GEMM: U[chunkM,1536] = split-f32 X[row_base..]*W_l -----------
// virtual K=1536: pass0 Xh*Wh, pass1 Xh*Wl, pass2 Xl*Wh. 128x128 tile,
// 4 waves (2x2 of 64x64), 16x16x32 bf16 MFMA, LDS stride 40 (bank-spread).
__global__ __launch_bounds__(256)
void gemm_kernel(const u16* __restrict__ Xh, const u16* __restrict__ Xl,
                 const u16* __restrict__ Ws,  // layer base [2][1536][512]
                 float* __restrict__ U, int row_base) {
  __shared__ u16 At[128][40];
  __shared__ u16 Bt[128][40];
  const int tid = threadIdx.x;
  const int row0 = blockIdx.x * 128;
  const int col0 = blockIdx.y * 128;
  const int lane = tid & 63, wave = tid >> 6;
  const int wm = (wave >> 1) * 64, wn = (wave & 1) * 64;
  const int m16 = lane & 15, quad = lane >> 4;
  const int srow = tid >> 1;       // staging row 0..127
  const int sk0 = (tid & 1) * 16;  // element offset {0,16}

  f32x4 acc[4][4];
#pragma unroll
  for (int mi = 0; mi < 4; ++mi)
#pragma unroll
    for (int ni = 0; ni < 4; ++ni)
#pragma unroll
      for (int r = 0; r < 4; ++r) acc[mi][ni][r] = 0.f;

  for (int kv = 0; kv < 1536; kv += 32) {
    int p = kv >> 9;
    int k0 = kv & 511;
    const u16* Asrc = (p == 2) ? Xl : Xh;
    const u16* Bsrc = Ws + ((p == 1) ? WPL : 0);

    size_t abase = (size_t)(row_base + row0 + srow) * DD + k0 + sk0;
    ushort8v a0 = *(const ushort8v*)(Asrc + abase);
    ushort8v a1 = *(const ushort8v*)(Asrc + abase + 8);
    size_t bbase = (size_t)(col0 + srow) * DD + k0 + sk0;
    ushort8v b0 = *(const ushort8v*)(Bsrc + bbase);
    ushort8v b1 = *(const ushort8v*)(Bsrc + bbase + 8);
    __syncthreads();
    *(ushort8v*)&At[srow][sk0] = a0;
    *(ushort8v*)&At[srow][sk0 + 8] = a1;
    *(ushort8v*)&Bt[srow][sk0] = b0;
    *(ushort8v*)&Bt[srow][sk0 + 8] = b1;
    __syncthreads();

    bshort8 af[4], bfr[4];
#pragma unroll
    for (int i = 0; i < 4; ++i) {
      af[i] = *(const bshort8*)&At[wm + i * 16 + m16][quad * 8];
      bfr[i] = *(const bshort8*)&Bt[wn + i * 16 + m16][quad * 8];
    }
#pragma unroll
    for (int mi = 0; mi < 4; ++mi)
#pragma unroll
      for (int ni = 0; ni < 4; ++ni)
        acc[mi][ni] = __builtin_amdgcn_mfma_f32_16x16x32_bf16(
            af[mi], bfr[ni], acc[mi][ni], 0, 0, 0);
  }

#pragma unroll
  for (int mi = 0; mi < 4; ++mi) {
    int r0 = row0 + wm + mi * 16 + quad * 4;
#pragma unroll
    for (int ni = 0; ni < 4; ++ni) {
      int cix = col0 + wn + ni * 16 + m16;
#pragma unroll
      for (int reg = 0; reg < 4; ++reg)
        U[(size_t)(r0 + reg) * N3 + cix] = acc[mi][ni][reg];
    }
  }
}

// ---- SRU scan, 8-deep prefetch; emits Xh/Xl for the next layer ---------
__global__ __launch_bounds__(64)
void scan_kernel(const float* __restrict__ U, float* __restrict__ X,
                 u16* __restrict__ Xh, u16* __restrict__ Xl,
                 const void* __restrict__ mask_p, const void* __restrict__ vbase,
                 const void* __restrict__ bbase, int layer,
                 const int* __restrict__ flags, float* __restrict__ carry,
                 int t0, int nt, int emit_hl) {
  __shared__ int msk[TT];
  int tid = threadIdx.x;
  int idx = blockIdx.x * 64 + tid;  // [0, B*D)
  int b = idx >> 9;
  int d = idx & 511;
  int ff = flags[0], fm = flags[1];

  const int* mi_ = (const int*)mask_p + b * TT;
  const unsigned char* mb_ = (const unsigned char*)mask_p + b * TT;
  for (int i = tid; i < nt; i += 64) msk[i] = fm ? (int)mb_[t0 + i] : mi_[t0 + i];
  __syncthreads();

  size_t voff = (size_t)layer * 2 * DD;
  float vf, vr, bf_, br_;
  if (ff) {
    const float* vp = (const float*)vbase + voff;
    const float* bp2 = (const float*)bbase + voff;
    vf = vp[d]; vr = vp[DD + d]; bf_ = bp2[d]; br_ = bp2[DD + d];
  } else {
    const u16* vp = (const u16*)vbase + voff;
    const u16* bp2 = (const u16*)bbase + voff;
    vf = b2f(vp[d]); vr = b2f(vp[DD + d]); bf_ = b2f(bp2[d]); br_ = b2f(bp2[DD + d]);
  }

  float c = (t0 == 0) ? 0.f : carry[idx];
  float* Xp = X + (size_t)b * TT * DD + d;

  float px[PF], pf[PF], pr[PF], pi[PF];
#pragma unroll
  for (int j = 0; j < PF; ++j) {
    if (j < nt) {
      const float* u = U + ((size_t)j * BB + b) * N3 + d;
      px[j] = u[0]; pf[j] = u[512]; pr[j] = u[1024];
      pi[j] = Xp[(size_t)(t0 + j) * DD];
    }
  }

  for (int tl0 = 0; tl0 < nt; tl0 += PF) {
#pragma unroll
    for (int j = 0; j < PF; ++j) {
      int tl = tl0 + j;
      float xt = px[j], fp = pf[j], rp = pr[j], xin = pi[j];
      int tn = tl + PF;
      if (tn < nt) {  // refill slot (c-independent loads, PF deep in flight)
        const float* u = U + ((size_t)tn * BB + b) * N3 + d;
        px[j] = u[0]; pf[j] = u[512]; pr[j] = u[1024];
        pi[j] = Xp[(size_t)(t0 + tn) * DD];
      }
      int m = msk[tl];
      float zf = fp + vf * c + bf_;
      float zr = rp + vr * c + br_;
      float f = 1.f / (1.f + __expf(-zf));
      float r = 1.f / (1.f + __expf(-zr));
      float cn = f * c + (1.f - f) * xt;
      float e2 = __expf(2.f * cn);
      float th = (e2 - 1.f) / (e2 + 1.f);
      float h = r * th + (1.f - r) * xin;
      bool pad = (m == 0);
      if (!pad) c = cn;
      float hout = pad ? 0.f : h;
      int tg = t0 + tl;
      Xp[(size_t)tg * DD] = hout;
      if (emit_hl) {
        u16 hi = f2b(hout);
        size_t o = ((size_t)tg * BB + b) * DD + d;
        Xh[o] = hi;
        Xl[o] = f2b(hout - b2f(hi));
      }
    }
  }
  carry[idx] = c;
}

__global__ void sentinel_kernel(float* out) { out[threadIdx.x] = 12345.f; }

extern "C" void kernel_launch(void* const* d_in, const int* in_sizes, int n_in,
                              void* d_out, int out_size, void* d_ws, size_t ws_size,
                              hipStream_t stream) {
  const int* ids = (const int*)d_in[0];
  const void* mask = d_in[1];
  const void* emb = d_in[2];
  const void* W = d_in[3];
  const void* v = d_in[4];
  const void* bp = d_in[5];

  char* ws = (char*)d_ws;
  int* flags = (int*)ws;                      // 4 KiB
  float* carry = (float*)(ws + 4096);         // 64 KiB
  const size_t offXh = 69632;
  const size_t offXl = offXh + (size_t)MROWS * DD * 2;  // +16 MiB
  const size_t offWs = offXl + (size_t)MROWS * DD * 2;  // +16 MiB
  const size_t offU = offWs + (size_t)LAYERS * 2 * WPL * 2;  // +12 MiB
  const size_t perT = (size_t)BB * N3 * 4;    // 196608 B / timestep

  const int cand[7] = {512, 256, 128, 64, 32, 16, 8};
  int chunkT = 0;
  for (int i = 0; i < 7; ++i) {
    if (ws_size >= offU + (size_t)cand[i] * perT) { chunkT = cand[i]; break; }
  }
  if (!chunkT) {
    sentinel_kernel<<<1, 256, 0, stream>>>((float*)d_out);
    return;
  }

  u16* Xh = (u16*)(ws + offXh);
  u16* Xl = (u16*)(ws + offXl);
  u16* Wst = (u16*)(ws + offWs);
  float* U = (float*)(ws + offU);
  float* X = (float*)d_out;  // (B,T,D) f32

  detect_kernel<<<1, 256, 0, stream>>>((const u16*)emb, (const int*)mask,
                                       (const int*)ids, flags);
  wprep_kernel<<<dim3(16, 48, 4), 256, 0, stream>>>(W, Wst, flags);
  embed_kernel<<<MROWS * DD / 256, 256, 0, stream>>>(ids, emb, X, Xh, Xl, flags);

  int nch = TT / chunkT;
  for (int l = 0; l < LAYERS; ++l) {
    const u16* Wsl = Wst + (size_t)l * 2 * WPL;
    for (int ch = 0; ch < nch; ++ch) {
      int t0 = ch * chunkT;
      dim3 g(chunkT * BB / 128, N3 / 128);
      gemm_kernel<<<g, 256, 0, stream>>>(Xh, Xl, Wsl, U, t0 * BB);
      scan_kernel<<<BB * DD / 64, 64, 0, stream>>>(U, X, Xh, Xl, mask, v, bp, l,
                                                   flags, carry, t0, chunkT,
                                                   (l < LAYERS - 1) ? 1 : 0);
    }
  }
}